// Round 1
// baseline (886.370 us; speedup 1.0000x reference)
//
#include <hip/hip_runtime.h>

// ROI pooling 3D: segment-mean of feat (2,64,96,112,96) over atlas (91,109,91), segs 1..94.
constexpr int SEG_N   = 95;            // NUM_SEG
constexpr int CROP_D  = 91, CROP_H = 109, CROP_W = 91;
constexpr int NVOX    = CROP_D * CROP_H * CROP_W;   // 902629
constexpr int FEAT_H  = 112, FEAT_W = 96;
constexpr int CSTRIDE = 96 * 112 * 96;              // per-channel elements = 1032192
constexpr int NBC     = 128;                        // B*C = 2*64
constexpr int CHUNK   = 1024;
constexpr int OUT_N   = 2 * 94 * 64;                // 12032

__global__ __launch_bounds__(256) void seg_accum(const float* __restrict__ feat,
                                                 const int*   __restrict__ atlas,
                                                 float* __restrict__ sums,   // [NBC][SEG_N]
                                                 int*   __restrict__ cnts)   // [SEG_N]
{
    __shared__ unsigned int meta[CHUNK];
    __shared__ float bins[NBC][SEG_N];
    __shared__ int   cbin[SEG_N];

    const int tid    = threadIdx.x;
    const int chunk0 = blockIdx.x * CHUNK;
    const int nvalid = min(CHUNK, NVOX - chunk0);

    // zero LDS accumulators
    for (int i = tid; i < NBC * SEG_N; i += 256) ((float*)bins)[i] = 0.0f;
    for (int i = tid; i < SEG_N; i += 256) cbin[i] = 0;
    __syncthreads();

    // phase 1: decode (id, spatial offset) once per voxel; shared by all 128 channels
    for (int i = tid; i < nvalid; i += 256) {
        const int n  = chunk0 + i;
        const int id = atlas[n];                       // [0, 95)
        const int w  = n % CROP_W;
        const int t  = n / CROP_W;
        const int h  = t % CROP_H;
        const int d  = t / CROP_H;
        const unsigned int off = (unsigned)(d * (FEAT_H * FEAT_W) + h * FEAT_W + w); // < 2^20
        meta[i] = (off << 7) | (unsigned)id;
        atomicAdd(&cbin[id], 1);
    }
    __syncthreads();

    // phase 2: each wave sweeps the chunk for bc = wave, wave+4, ...
    const int wv   = tid >> 6;
    const int lane = tid & 63;
    for (int bc = wv; bc < NBC; bc += 4) {
        const float* __restrict__ fp = feat + (size_t)bc * CSTRIDE;
        float* __restrict__ b = bins[bc];
        for (int i = lane; i < nvalid; i += 64) {
            const unsigned int m = meta[i];
            const float v = fp[m >> 7];
            atomicAdd(&b[m & 127u], v);               // ds_add_f32
        }
    }
    __syncthreads();

    // flush block-partial sums to global
    for (int i = tid; i < NBC * SEG_N; i += 256)
        unsafeAtomicAdd(&sums[i], ((float*)bins)[i]);
    for (int i = tid; i < SEG_N; i += 256)
        atomicAdd(&cnts[i], cbin[i]);
}

__global__ __launch_bounds__(256) void finalize(const float* __restrict__ sums,
                                                const int*   __restrict__ cnts,
                                                float* __restrict__ out)
{
    const int idx = blockIdx.x * 256 + threadIdx.x;
    if (idx >= OUT_N) return;
    const int c  = idx & 63;
    const int s  = (idx >> 6) % 94;       // 0..93 -> segment s+1
    const int b  = idx / (94 * 64);
    const int bc = b * 64 + c;
    const float den = fmaxf((float)cnts[s + 1], 1e-6f);
    out[idx] = sums[bc * SEG_N + (s + 1)] / den;
}

extern "C" void kernel_launch(void* const* d_in, const int* in_sizes, int n_in,
                              void* d_out, int out_size, void* d_ws, size_t ws_size,
                              hipStream_t stream)
{
    const float* feat  = (const float*)d_in[0];
    const int*   atlas = (const int*)d_in[1];
    float* out  = (float*)d_out;
    float* sums = (float*)d_ws;                                  // NBC*SEG_N floats
    int*   cnts = (int*)((char*)d_ws + (size_t)NBC * SEG_N * sizeof(float));

    hipMemsetAsync(d_ws, 0, (size_t)(NBC * SEG_N + SEG_N) * sizeof(int), stream);

    const int nblk = (NVOX + CHUNK - 1) / CHUNK;                 // 882
    seg_accum<<<nblk, 256, 0, stream>>>(feat, atlas, sums, cnts);
    finalize<<<(OUT_N + 255) / 256, 256, 0, stream>>>(sums, cnts, out);
}

// Round 2
// 657.759 us; speedup vs baseline: 1.3476x; 1.3476x over previous
//
#include <hip/hip_runtime.h>

// ROI pooling 3D: segment-mean of feat (2,64,96,112,96) fp32 over atlas (91,109,91), segs 1..94.
constexpr int SEG_N   = 95;
constexpr int CROP_D  = 91, CROP_H = 109, CROP_W = 91;
constexpr int NVOX    = CROP_D * CROP_H * CROP_W;     // 902629
constexpr int LINES   = CROP_D * CROP_H;              // 9919 (d,h) lines
constexpr int FEAT_W  = 96;
constexpr int FEAT_HW = 112 * 96;                     // d-stride in feat
constexpr int CSTRIDE = 96 * 112 * 96;                // per-(b,c) channel elements
constexpr int NBC     = 128;                          // B*C
constexpr int HBC     = 64;                           // channels per block
constexpr int TL      = 16;                           // lines per tile
constexpr int NTILES  = (LINES + TL - 1) / TL;        // 620
constexpr int BINC    = 96;                           // 95 segs + trash col (w>=91 / pad lines)
constexpr int OUT_N   = 2 * 94 * 64;

// Main accumulator: coalesced float4 line reads, LDS-binned ds_add_f32.
__global__ __launch_bounds__(256) void seg_accum(const float* __restrict__ feat,
                                                 const int*   __restrict__ atlas,
                                                 float* __restrict__ sums)   // [NBC][SEG_N]
{
    __shared__ float bins[HBC][BINC];                 // 24 KB
    __shared__ unsigned char meta[TL * FEAT_W];       // 1536 B: seg id per padded voxel
    __shared__ int lbase[TL];                         // feat element offset of each line

    const int tid  = threadIdx.x;
    const int tile = blockIdx.x >> 1;
    const int half = blockIdx.x & 1;                  // which 64 channels

    for (int i = tid; i < HBC * BINC; i += 256) ((float*)bins)[i] = 0.0f;
    if (tid < TL) {
        const int gl = tile * TL + tid;
        lbase[tid] = (gl < LINES) ? (gl / CROP_H) * FEAT_HW + (gl % CROP_H) * FEAT_W : 0;
    }
    for (int i = tid; i < TL * FEAT_W; i += 256) {
        const int line = i / FEAT_W, w = i - line * FEAT_W;
        const int gl   = tile * TL + line;
        int id = 95;                                  // trash column
        if (w < CROP_W && gl < LINES) id = atlas[gl * CROP_W + w];
        meta[i] = (unsigned char)id;
    }
    __syncthreads();

    const int wv = tid >> 6, lane = tid & 63;
    // Per-lane tile geometry: fixed across all channels. 6 float4s cover 1536 floats/wave.
    unsigned int goff[6], mid[6];
    #pragma unroll
    for (int it = 0; it < 6; ++it) {
        const int f    = it * 256 + lane * 4;         // flat padded-voxel index in tile
        const int line = f / FEAT_W;
        goff[it] = (unsigned)(lbase[line] + (f - line * FEAT_W));
        mid[it]  = *(const unsigned int*)&meta[f];    // 4 packed u8 seg ids
    }

    #pragma unroll 2
    for (int u = 0; u < 16; ++u) {
        const int bcl = wv * 16 + u;                  // local channel 0..63
        const float* __restrict__ fb = feat + (size_t)(half * HBC + bcl) * CSTRIDE;
        #pragma unroll
        for (int it = 0; it < 6; ++it) {
            const float4 v = *(const float4*)(fb + goff[it]);
            const unsigned int m = mid[it];
            atomicAdd(&bins[bcl][m & 255u],         v.x);
            atomicAdd(&bins[bcl][(m >> 8)  & 255u], v.y);
            atomicAdd(&bins[bcl][(m >> 16) & 255u], v.z);
            atomicAdd(&bins[bcl][m >> 24],          v.w);
        }
    }
    __syncthreads();

    for (int i = tid; i < HBC * SEG_N; i += 256) {
        const int bcl = i / SEG_N, s = i - bcl * SEG_N;
        unsafeAtomicAdd(&sums[(half * HBC + bcl) * SEG_N + s], bins[bcl][s]);
    }
}

__global__ __launch_bounds__(256) void seg_count(const int* __restrict__ atlas,
                                                 int* __restrict__ cnts)
{
    __shared__ int cbin[SEG_N];
    const int tid = threadIdx.x;
    for (int i = tid; i < SEG_N; i += 256) cbin[i] = 0;
    __syncthreads();
    for (int i = blockIdx.x * 256 + tid; i < NVOX; i += gridDim.x * 256)
        atomicAdd(&cbin[atlas[i]], 1);
    __syncthreads();
    for (int i = tid; i < SEG_N; i += 256) atomicAdd(&cnts[i], cbin[i]);
}

__global__ __launch_bounds__(256) void finalize(const float* __restrict__ sums,
                                                const int*   __restrict__ cnts,
                                                float* __restrict__ out)
{
    const int idx = blockIdx.x * 256 + threadIdx.x;
    if (idx >= OUT_N) return;
    const int c  = idx & 63;
    const int s  = (idx >> 6) % 94;                   // segment s+1
    const int b  = idx / (94 * 64);
    const int bc = b * 64 + c;
    const float den = fmaxf((float)cnts[s + 1], 1e-6f);
    out[idx] = sums[bc * SEG_N + (s + 1)] / den;
}

extern "C" void kernel_launch(void* const* d_in, const int* in_sizes, int n_in,
                              void* d_out, int out_size, void* d_ws, size_t ws_size,
                              hipStream_t stream)
{
    const float* feat  = (const float*)d_in[0];
    const int*   atlas = (const int*)d_in[1];
    float* out  = (float*)d_out;
    float* sums = (float*)d_ws;                                   // NBC*SEG_N floats
    int*   cnts = (int*)((char*)d_ws + (size_t)NBC * SEG_N * sizeof(float));

    hipMemsetAsync(d_ws, 0, (size_t)(NBC * SEG_N + SEG_N) * sizeof(int), stream);

    seg_count<<<256, 256, 0, stream>>>(atlas, cnts);
    seg_accum<<<NTILES * 2, 256, 0, stream>>>(feat, atlas, sums);
    finalize<<<(OUT_N + 255) / 256, 256, 0, stream>>>(sums, cnts, out);
}